// Round 24
// baseline (422.057 us; speedup 1.0000x reference)
//
#include <hip/hip_runtime.h>
#include <cstddef>

#define NN 3072
#define RR 16
#define NB 16
#define FILL_BLOCKS 64
#define FILL_ITERS 2304  // NN*NN*4 quads / (FILL_BLOCKS*256 threads) = 2304 exactly

typedef float f32x4 __attribute__((ext_vector_type(4)));

// Prologue: key[i] = valid ? batch[i] : -1, plus batch row boundaries
// start[b] = first row with batch >= b (batch sorted). start[NB]=NN.
__global__ void frd_prep_kernel(const int* __restrict__ cls,
                                const int* __restrict__ batch,
                                int* __restrict__ key,
                                int* __restrict__ start) {
    int t = blockIdx.x * blockDim.x + threadIdx.x;
    if (t < NN) {
        int c = cls[t];
        int b = batch[t];
        key[t] = (c != 24 && c != 25 && c != 26) ? b : -1;
        int prev = (t == 0) ? -1 : batch[t - 1];
        for (int bb = prev + 1; bb <= b; ++bb) start[bb] = t;
        if (t == NN - 1)
            for (int bb = b + 1; bb <= NB; ++bb) start[bb] = NN;
    }
}

// Phase 2: masked NT fill at the proven-optimal 64-block grid-stride
// geometry. Writes the default to every pair EXCEPT key-match pairs
// (ki>=0 && ki==kj) — those belong exclusively to diag. Write sets of the
// two dispatches are DISJOINT at 64 B line granularity: no cross-dispatch
// write ordering is required (fixes R23's replay race). Mask uses only
// L1-resident key[] (12 KB); 4 lanes of a pair share the skip decision so
// skipped pairs drop whole lines (no partial-line RMW).
__global__ __launch_bounds__(256)
void frd_fill_kernel(const int* __restrict__ key, float* __restrict__ out) {
    const int t = blockIdx.x * 256 + threadIdx.x;        // [0, 16384)
    const float d0 = ((t & 3) == 0) ? 1.0f : 0.0f;
    const f32x4 r = {d0, 0.0f, 0.0f, 0.0f};
    int quad = t;
    const int step = FILL_BLOCKS * 256;                  // 16384 quads per sweep
#pragma unroll 8
    for (int it = 0; it < FILL_ITERS; ++it) {
        const int pair = quad >> 2;                      // 4 lanes share a pair
        const int i = pair / NN;                         // magic-mul
        const int j = pair - i * NN;
        const int ki = key[i];                           // L1-resident
        const int kj = key[j];
        const bool skip = (ki >= 0) && (ki == kj);       // diag owns these
        if (!skip)
            __builtin_nontemporal_store(r, reinterpret_cast<f32x4*>(out + (size_t)quad * 4));
        quad += step;
    }
}

// Phase 3: key-match writer. One block per row i (exit if key invalid).
// 4 lanes per pair (lane q writes quad q) -> full 64 B coalesced lines.
// Writes product if seg_eff==0 else the default — exactly the pairs the
// fill skipped.
__global__ __launch_bounds__(256)
void frd_diag_kernel(const float* __restrict__ z1,
                     const float* __restrict__ z2,
                     const float* __restrict__ seg,
                     const int* __restrict__ key,
                     const int* __restrict__ start,
                     float* __restrict__ out) {
    const int i = blockIdx.x;
    const int ki = key[i];
    if (ki < 0) return;
    const int s0 = start[ki];
    const int s1 = start[ki + 1];
    const int q = threadIdx.x & 3;
    const int g = threadIdx.x >> 2;       // pair group [0,64)

    const float4 a = *reinterpret_cast<const float4*>(z1 + i * RR + q * 4);
    const float d0 = (q == 0) ? 1.0f : 0.0f;

    for (int j = s0 + g; j < s1; j += 64) {
        if (key[j] != ki) continue;                   // fill wrote this pair
        const float s = seg[i * NN + j];              // 4-lane broadcast
        const float seg_eff = s + ((i == j) ? 1.0f : 0.0f);
        f32x4 r;
        if (seg_eff == 0.0f) {
            const float4 b = *reinterpret_cast<const float4*>(z2 + j * RR + q * 4);
            r.x = a.x * b.x; r.y = a.y * b.y; r.z = a.z * b.z; r.w = a.w * b.w;
        } else {
            r.x = d0; r.y = 0.0f; r.z = 0.0f; r.w = 0.0f;
        }
        float* op = out + ((size_t)i * NN + j) * RR + q * 4;
        __builtin_nontemporal_store(r, reinterpret_cast<f32x4*>(op));
    }
}

extern "C" void kernel_launch(void* const* d_in, const int* in_sizes, int n_in,
                              void* d_out, int out_size, void* d_ws, size_t ws_size,
                              hipStream_t stream) {
    const float* z1  = (const float*)d_in[0];
    const float* z2  = (const float*)d_in[1];
    const float* seg = (const float*)d_in[2];
    const int* cls   = (const int*)d_in[3];
    const int* batch = (const int*)d_in[4];
    float* out = (float*)d_out;
    int* key   = (int*)d_ws;
    int* start = key + NN;

    frd_prep_kernel<<<(NN + 255) / 256, 256, 0, stream>>>(cls, batch, key, start);
    frd_fill_kernel<<<FILL_BLOCKS, 256, 0, stream>>>(key, out);
    frd_diag_kernel<<<NN, 256, 0, stream>>>(z1, z2, seg, key, start, out);
}

// Round 25
// 122.933 us; speedup vs baseline: 3.4332x; 3.4332x over previous
//
#include <hip/hip_runtime.h>
#include <cstddef>

#define NN 3072
#define RR 16
#define NB 16
#define FILL_BLOCKS 64

typedef float f32x4 __attribute__((ext_vector_type(4)));

// Prologue: key[i] = valid ? batch[i] : -1, plus batch row boundaries
// start[b] = first row with batch >= b (batch sorted). start[NB]=NN.
__global__ void frd_prep_kernel(const int* __restrict__ cls,
                                const int* __restrict__ batch,
                                int* __restrict__ key,
                                int* __restrict__ start) {
    int t = blockIdx.x * blockDim.x + threadIdx.x;
    if (t < NN) {
        int c = cls[t];
        int b = batch[t];
        key[t] = (c != 24 && c != 25 && c != 26) ? b : -1;
        int prev = (t == 0) ? -1 : batch[t - 1];
        for (int bb = prev + 1; bb <= b; ++bb) start[bb] = t;
        if (t == NN - 1)
            for (int bb = b + 1; bb <= NB; ++bb) start[bb] = NN;
    }
}

// Phase 2: row-structured NT fill, 64 blocks (proven-optimal stream count).
// Block b sweeps rows b, b+64, ... For each row, writes the default to the
// columns OUTSIDE the row's batch range [s0,s1) (whole row if key invalid).
// All stores are unconditional and load-free (the 3 per-row scalar loads are
// hoisted out of the store loops) — preserves the fire-and-forget issue that
// makes the 64-block fill run at 6.3 TB/s. Row segments are pair-aligned ->
// whole 64 B lines; diag owns [s0,s1) of valid rows exclusively (disjoint).
__global__ __launch_bounds__(256)
void frd_fill_kernel(const int* __restrict__ key,
                     const int* __restrict__ start,
                     float* __restrict__ out) {
    const int tid = threadIdx.x;
    const float d0 = ((tid & 3) == 0) ? 1.0f : 0.0f;   // one_hot(0,R) head
    const f32x4 r = {d0, 0.0f, 0.0f, 0.0f};
    const int rowquads = NN * 4;                        // 12288 quads per row

    for (int i = blockIdx.x; i < NN; i += FILL_BLOCKS) {
        const int ki = key[i];                          // wave-uniform scalar
        int e0 = rowquads, b1 = rowquads;               // invalid row: whole row
        if (ki >= 0) {
            e0 = start[ki] * 4;                         // segment A end (quads)
            b1 = start[ki + 1] * 4;                     // segment B begin
        }
        float* rowp = out + (size_t)i * NN * RR;
        for (int q = tid; q < e0; q += 256)
            __builtin_nontemporal_store(r, reinterpret_cast<f32x4*>(rowp + (size_t)q * 4));
        for (int q = b1 + tid; q < rowquads; q += 256)
            __builtin_nontemporal_store(r, reinterpret_cast<f32x4*>(rowp + (size_t)q * 4));
    }
}

// Phase 3: batch-range writer. One block per row i (exit if key invalid).
// Writes the ENTIRE [s0,s1) range: product if key[j]==ki && seg_eff==0,
// else the default. 4 lanes per pair -> full 64 B coalesced lines.
__global__ __launch_bounds__(256)
void frd_diag_kernel(const float* __restrict__ z1,
                     const float* __restrict__ z2,
                     const float* __restrict__ seg,
                     const int* __restrict__ key,
                     const int* __restrict__ start,
                     float* __restrict__ out) {
    const int i = blockIdx.x;
    const int ki = key[i];
    if (ki < 0) return;
    const int s0 = start[ki];
    const int s1 = start[ki + 1];
    const int q = threadIdx.x & 3;
    const int g = threadIdx.x >> 2;       // pair group [0,64)

    const float4 a = *reinterpret_cast<const float4*>(z1 + i * RR + q * 4);
    const float d0 = (q == 0) ? 1.0f : 0.0f;

    for (int j = s0 + g; j < s1; j += 64) {
        f32x4 r = {d0, 0.0f, 0.0f, 0.0f};
        if (key[j] == ki) {
            const float s = seg[i * NN + j];          // 4-lane broadcast
            const float seg_eff = s + ((i == j) ? 1.0f : 0.0f);
            if (seg_eff == 0.0f) {
                const float4 b = *reinterpret_cast<const float4*>(z2 + j * RR + q * 4);
                r.x = a.x * b.x; r.y = a.y * b.y; r.z = a.z * b.z; r.w = a.w * b.w;
            }
        }
        float* op = out + ((size_t)i * NN + j) * RR + q * 4;
        __builtin_nontemporal_store(r, reinterpret_cast<f32x4*>(op));
    }
}

extern "C" void kernel_launch(void* const* d_in, const int* in_sizes, int n_in,
                              void* d_out, int out_size, void* d_ws, size_t ws_size,
                              hipStream_t stream) {
    const float* z1  = (const float*)d_in[0];
    const float* z2  = (const float*)d_in[1];
    const float* seg = (const float*)d_in[2];
    const int* cls   = (const int*)d_in[3];
    const int* batch = (const int*)d_in[4];
    float* out = (float*)d_out;
    int* key   = (int*)d_ws;
    int* start = key + NN;

    frd_prep_kernel<<<(NN + 255) / 256, 256, 0, stream>>>(cls, batch, key, start);
    frd_fill_kernel<<<FILL_BLOCKS, 256, 0, stream>>>(key, start, out);
    frd_diag_kernel<<<NN, 256, 0, stream>>>(z1, z2, seg, key, start, out);
}